// Round 3
// baseline (2882.218 us; speedup 1.0000x reference)
//
#include <hip/hip_runtime.h>
#include <hip/hip_bf16.h>
#include <math.h>

#define BB      32
#define CC      256
#define HDIM    56
#define NPIX    3136
#define NHEADS  8
#define HD      32
#define AG      49
#define NGROUPS 32
#define CPG     8
#define SCALE   0.17677669529663687f

// ---------------- conv1x1: Y[b][o][n] = sum_c W[o][c] * X[b][c][n] ----------
// per-batch GEMM M=256,K=256,N=3136; 64x64 tile, BK=16, 256 thr, 4x4/thread
__global__ __launch_bounds__(256) void conv1x1_kernel(
    const float* __restrict__ X, const float* __restrict__ W,
    float* __restrict__ Y) {
  __shared__ float Ws[16][64];
  __shared__ float Xs[16][64];
  const int n0 = blockIdx.x * 64;
  const int o0 = blockIdx.y * 64;
  const int b  = blockIdx.z;
  const float* Xb = X + (size_t)b * CC * NPIX;
  float* Yb = Y + (size_t)b * CC * NPIX;
  const int tid = threadIdx.x;
  const int tx = tid & 15, ty = tid >> 4;
  const int wo = tid >> 2, wk = (tid & 3) << 2;
  const int xk = tid >> 4, xn = (tid & 15) << 2;
  float acc[4][4] = {};
  for (int k0 = 0; k0 < CC; k0 += 16) {
    float4 wv = *(const float4*)&W[(size_t)(o0 + wo) * CC + k0 + wk];
    Ws[wk + 0][wo] = wv.x; Ws[wk + 1][wo] = wv.y;
    Ws[wk + 2][wo] = wv.z; Ws[wk + 3][wo] = wv.w;
    *(float4*)&Xs[xk][xn] =
        *(const float4*)&Xb[(size_t)(k0 + xk) * NPIX + n0 + xn];
    __syncthreads();
#pragma unroll
    for (int kk = 0; kk < 16; ++kk) {
      const float a0 = Ws[kk][ty * 4 + 0];
      const float a1 = Ws[kk][ty * 4 + 1];
      const float a2 = Ws[kk][ty * 4 + 2];
      const float a3 = Ws[kk][ty * 4 + 3];
      const float4 bv = *(const float4*)&Xs[kk][tx * 4];
      acc[0][0] += a0 * bv.x; acc[0][1] += a0 * bv.y;
      acc[0][2] += a0 * bv.z; acc[0][3] += a0 * bv.w;
      acc[1][0] += a1 * bv.x; acc[1][1] += a1 * bv.y;
      acc[1][2] += a1 * bv.z; acc[1][3] += a1 * bv.w;
      acc[2][0] += a2 * bv.x; acc[2][1] += a2 * bv.y;
      acc[2][2] += a2 * bv.z; acc[2][3] += a2 * bv.w;
      acc[3][0] += a3 * bv.x; acc[3][1] += a3 * bv.y;
      acc[3][2] += a3 * bv.z; acc[3][3] += a3 * bv.w;
    }
    __syncthreads();
  }
#pragma unroll
  for (int i = 0; i < 4; ++i) {
    float4 r = make_float4(acc[i][0], acc[i][1], acc[i][2], acc[i][3]);
    *(float4*)&Yb[(size_t)(o0 + ty * 4 + i) * NPIX + n0 + tx * 4] = r;
  }
}

// ---------------- GroupNorm (in-place capable): one block per (b, g) --------
__global__ __launch_bounds__(256) void gn_kernel(
    const float* __restrict__ in, const float* __restrict__ gw,
    const float* __restrict__ gb, float* __restrict__ out) {
  const int g = blockIdx.x, b = blockIdx.y;
  const float* p = in + ((size_t)b * CC + g * CPG) * NPIX;
  float* q = out + ((size_t)b * CC + g * CPG) * NPIX;
  const int tid = threadIdx.x;
  const int M4 = CPG * NPIX / 4;  // 6272 float4s
  const float4* p4 = (const float4*)p;
  float4* q4 = (float4*)q;
  float s = 0.f, ss = 0.f;
  for (int i = tid; i < M4; i += 256) {
    float4 v = p4[i];
    s += v.x + v.y + v.z + v.w;
    ss += v.x * v.x + v.y * v.y + v.z * v.z + v.w * v.w;
  }
#pragma unroll
  for (int off = 32; off > 0; off >>= 1) {
    s += __shfl_down(s, off);
    ss += __shfl_down(ss, off);
  }
  __shared__ float wsum[4], wsq[4], stat[2];
  const int wv = tid >> 6, ln = tid & 63;
  if (ln == 0) { wsum[wv] = s; wsq[wv] = ss; }
  __syncthreads();
  if (tid == 0) {
    float S = wsum[0] + wsum[1] + wsum[2] + wsum[3];
    float SS = wsq[0] + wsq[1] + wsq[2] + wsq[3];
    const float inv_m = 1.f / (CPG * NPIX);
    float mean = S * inv_m;
    float var = SS * inv_m - mean * mean;
    stat[0] = mean;
    stat[1] = rsqrtf(var + 1e-5f);
  }
  __syncthreads();
  const float mean = stat[0], inv = stat[1];
  for (int i = tid; i < M4; i += 256) {
    const int ch = g * CPG + i / (NPIX / 4);
    const float w = gw[ch] * inv, bia = gb[ch];
    float4 v = p4[i];
    v.x = (v.x - mean) * w + bia;
    v.y = (v.y - mean) * w + bia;
    v.z = (v.z - mean) * w + bia;
    v.w = (v.w - mean) * w + bia;
    q4[i] = v;
  }
}

// ---------------- agent-token pool: 8x8 avg -> (B,C,49) ---------------------
__global__ __launch_bounds__(64) void pool_kernel(const float* __restrict__ q,
                                                  float* __restrict__ at) {
  const int bc = blockIdx.x;
  const int a = threadIdx.x;
  if (a >= AG) return;
  const int py = a / 7, px = a % 7;
  const float* p = q + (size_t)bc * NPIX + (py * 8) * HDIM + px * 8;
  float s = 0.f;
#pragma unroll
  for (int y = 0; y < 8; ++y)
#pragma unroll
    for (int x = 0; x < 8; ++x) s += p[y * HDIM + x];
  at[(size_t)bc * AG + a] = s * (1.f / 64.f);
}

// ---------------- bias precompute -------------------------------------------
// bilinear 7->56 with half-pixel centers == clamped-coordinate bilinear
__device__ __forceinline__ float bilin7(const float* __restrict__ src, int y,
                                        int x) {
  float sy = fminf(fmaxf((y + 0.5f) * 0.125f - 0.5f, 0.f), 6.f);
  float sx = fminf(fmaxf((x + 0.5f) * 0.125f - 0.5f, 0.f), 6.f);
  int y0 = (int)sy, x0 = (int)sx;
  int y1 = min(y0 + 1, 6), x1 = min(x0 + 1, 6);
  float fy = sy - y0, fx = sx - x0;
  return (1.f - fy) * ((1.f - fx) * src[y0 * 7 + x0] + fx * src[y0 * 7 + x1]) +
         fy * ((1.f - fx) * src[y1 * 7 + x0] + fx * src[y1 * 7 + x1]);
}

// pb[h][a][n] = resize(an_bias)[h,a,n] + ah[h,a,y] + aw[h,a,x]
__global__ __launch_bounds__(256) void bias1_kernel(
    const float* __restrict__ an, const float* __restrict__ ah,
    const float* __restrict__ aw, float* __restrict__ pb) {
  const int ha = blockIdx.x;  // h*AG + a
  const float* src = an + (size_t)ha * 49;
  const float* ahp = ah + (size_t)ha * HDIM;
  const float* awp = aw + (size_t)ha * HDIM;
  float* dst = pb + (size_t)ha * NPIX;
  for (int n = threadIdx.x; n < NPIX; n += 256) {
    const int y = n / HDIM, x = n % HDIM;
    dst[n] = bilin7(src, y, x) + ahp[y] + awp[x];
  }
}

// ab[h][n][a] = resize(na_bias)[h,a,n] + ha[h,y,a] + wa[h,x,a]
__global__ __launch_bounds__(256) void bias2_kernel(
    const float* __restrict__ na, const float* __restrict__ hab,
    const float* __restrict__ wab, float* __restrict__ ab) {
  const int ha = blockIdx.x;  // h*AG + a
  const int h = ha / AG, a = ha % AG;
  const float* src = na + (size_t)ha * 49;
  for (int n = threadIdx.x; n < NPIX; n += 256) {
    const int y = n / HDIM, x = n % HDIM;
    ab[((size_t)h * NPIX + n) * AG + a] =
        bilin7(src, y, x) + hab[((size_t)h * HDIM + y) * AG + a] +
        wab[((size_t)h * HDIM + x) * AG + a];
  }
}

// ---------------- stage 1: agents attend to keys; agent_v -------------------
// one block per (b,h,a); 256 threads; softmax over N=3136
__global__ __launch_bounds__(256) void stage1_kernel(
    const float* __restrict__ K, const float* __restrict__ V,
    const float* __restrict__ at, const float* __restrict__ pb,
    float* __restrict__ av) {
  const int idx = blockIdx.x;
  const int a = idx % AG;
  const int bh = idx / AG;
  const int h = bh % NHEADS, b = bh / NHEADS;
  __shared__ float at_s[HD];
  const int tid = threadIdx.x;
  if (tid < HD)
    at_s[tid] = at[((size_t)b * CC + h * HD + tid) * AG + a] * SCALE;
  __syncthreads();
  const float* Kb = K + ((size_t)b * CC + h * HD) * NPIX;
  const float* Vb = V + ((size_t)b * CC + h * HD) * NPIX;
  const float* pbh = pb + ((size_t)h * AG + a) * NPIX;
  float lg[13];
  float lmax = -1e30f;
#pragma unroll
  for (int i = 0; i < 13; ++i) {
    const int n = tid + i * 256;
    if (n < NPIX) {
      float s = pbh[n];
#pragma unroll
      for (int d = 0; d < HD; ++d) s += at_s[d] * Kb[(size_t)d * NPIX + n];
      lg[i] = s;
      lmax = fmaxf(lmax, s);
    }
  }
#pragma unroll
  for (int off = 32; off > 0; off >>= 1) lmax = fmaxf(lmax, __shfl_down(lmax, off));
  __shared__ float red[4];
  const int wv = tid >> 6, ln = tid & 63;
  if (ln == 0) red[wv] = lmax;
  __syncthreads();
  const float bmax = fmaxf(fmaxf(red[0], red[1]), fmaxf(red[2], red[3]));
  __syncthreads();
  float lsum = 0.f;
#pragma unroll
  for (int i = 0; i < 13; ++i) {
    const int n = tid + i * 256;
    if (n < NPIX) {
      float e = __expf(lg[i] - bmax);
      lg[i] = e;
      lsum += e;
    }
  }
#pragma unroll
  for (int off = 32; off > 0; off >>= 1) lsum += __shfl_down(lsum, off);
  if (ln == 0) red[wv] = lsum;
  __syncthreads();
  const float invs = 1.f / (red[0] + red[1] + red[2] + red[3]);
  float accd[HD];
#pragma unroll
  for (int d = 0; d < HD; ++d) accd[d] = 0.f;
#pragma unroll
  for (int i = 0; i < 13; ++i) {
    const int n = tid + i * 256;
    if (n < NPIX) {
      const float p = lg[i];
#pragma unroll
      for (int d = 0; d < HD; ++d) accd[d] += p * Vb[(size_t)d * NPIX + n];
    }
  }
#pragma unroll
  for (int d = 0; d < HD; ++d) {
#pragma unroll
    for (int off = 32; off > 0; off >>= 1) accd[d] += __shfl_down(accd[d], off);
  }
  __shared__ float part[4][HD];
  if (ln == 0) {
#pragma unroll
    for (int d = 0; d < HD; ++d) part[wv][d] = accd[d];
  }
  __syncthreads();
  if (tid < HD) {
    const float r = (part[0][tid] + part[1][tid]) + (part[2][tid] + part[3][tid]);
    av[(((size_t)b * NHEADS + h) * AG + a) * HD + tid] = r * invs;
  }
}

// ---------------- stage 2: queries attend to agents; writes xo in place -----
// grid (13, HEADS, B), 256 thr; thread = one pixel n
__global__ __launch_bounds__(256) void stage2_kernel(
    const float* __restrict__ Q, const float* __restrict__ at,
    const float* __restrict__ av, const float* __restrict__ ab,
    float* __restrict__ XO) {
  const int tid = threadIdx.x;
  const int n = blockIdx.x * 256 + tid;
  const int h = blockIdx.y, b = blockIdx.z;
  __shared__ float at_s[AG][HD];
  __shared__ float av_s[AG][HD];
  for (int i = tid; i < AG * HD; i += 256) {
    const int a = i / HD, d = i % HD;
    at_s[a][d] = at[((size_t)b * CC + h * HD + d) * AG + a];
    av_s[a][d] = av[(((size_t)b * NHEADS + h) * AG + a) * HD + d];
  }
  __syncthreads();
  if (n >= NPIX) return;
  const float* Qb = Q + ((size_t)b * CC + h * HD) * NPIX;
  float* Ob = XO + ((size_t)b * CC + h * HD) * NPIX;
  float qv[HD];
#pragma unroll
  for (int d = 0; d < HD; ++d) qv[d] = Qb[(size_t)d * NPIX + n] * SCALE;
  const float* abp = ab + ((size_t)h * NPIX + n) * AG;
  // pass 1: max
  float m = -1e30f;
  for (int a = 0; a < AG; ++a) {
    float s = abp[a];
#pragma unroll
    for (int d = 0; d < HD; ++d) s += qv[d] * at_s[a][d];
    m = fmaxf(m, s);
  }
  // pass 2: exp-sum + PV accumulate
  float sum = 0.f;
  float o[HD];
#pragma unroll
  for (int d = 0; d < HD; ++d) o[d] = 0.f;
  for (int a = 0; a < AG; ++a) {
    float s = abp[a];
#pragma unroll
    for (int d = 0; d < HD; ++d) s += qv[d] * at_s[a][d];
    const float e = __expf(s - m);
    sum += e;
#pragma unroll
    for (int d = 0; d < HD; ++d) o[d] += e * av_s[a][d];
  }
  const float inv = 1.f / sum;
#pragma unroll
  for (int d = 0; d < HD; ++d) Ob[(size_t)d * NPIX + n] = o[d] * inv;
}

// ---------------- depthwise 3x3 conv on v, accumulate into XO ---------------
__global__ __launch_bounds__(256) void dwconv_kernel(
    const float* __restrict__ V, const float* __restrict__ w,
    const float* __restrict__ bias, float* __restrict__ XO) {
  const int bc = blockIdx.x;
  const int c = bc % CC;
  const float* src = V + (size_t)bc * NPIX;
  float* dst = XO + (size_t)bc * NPIX;
  float k[9];
#pragma unroll
  for (int i = 0; i < 9; ++i) k[i] = w[c * 9 + i];
  const float bb = bias[c];
  for (int n = threadIdx.x; n < NPIX; n += 256) {
    const int y = n / HDIM, x = n % HDIM;
    float s = bb;
#pragma unroll
    for (int ky = 0; ky < 3; ++ky) {
      const int yy = y + ky - 1;
      if (yy < 0 || yy >= HDIM) continue;
#pragma unroll
      for (int kx = 0; kx < 3; ++kx) {
        const int xx = x + kx - 1;
        if (xx < 0 || xx >= HDIM) continue;
        s += src[yy * HDIM + xx] * k[ky * 3 + kx];
      }
    }
    dst[n] += s;
  }
}

// ---------------- host launch ------------------------------------------------
extern "C" void kernel_launch(void* const* d_in, const int* in_sizes, int n_in,
                              void* d_out, int out_size, void* d_ws,
                              size_t ws_size, hipStream_t stream) {
  const float* x     = (const float*)d_in[0];
  const float* q_w   = (const float*)d_in[1];
  const float* q_gw  = (const float*)d_in[2];
  const float* q_gb  = (const float*)d_in[3];
  const float* k_w   = (const float*)d_in[4];
  const float* k_gw  = (const float*)d_in[5];
  const float* k_gb  = (const float*)d_in[6];
  const float* v_w   = (const float*)d_in[7];
  const float* v_gw  = (const float*)d_in[8];
  const float* v_gb  = (const float*)d_in[9];
  const float* p_w   = (const float*)d_in[10];
  const float* p_gw  = (const float*)d_in[11];
  const float* p_gb  = (const float*)d_in[12];
  const float* dwc_w = (const float*)d_in[13];
  const float* dwc_b = (const float*)d_in[14];
  const float* an_b  = (const float*)d_in[15];
  const float* na_b  = (const float*)d_in[16];
  const float* ah_b  = (const float*)d_in[17];
  const float* aw_b  = (const float*)d_in[18];
  const float* ha_b  = (const float*)d_in[19];
  const float* wa_b  = (const float*)d_in[20];
  float* out = (float*)d_out;

  const size_t SZ_FEAT = (size_t)BB * CC * NPIX;       // 25,690,112 floats
  const size_t SZ_AT   = (size_t)BB * CC * AG;         // 401,408
  const size_t SZ_PB   = (size_t)NHEADS * AG * NPIX;   // 1,229,312
  const size_t SZ_AV   = (size_t)BB * NHEADS * AG * HD;
  const size_t need = (3 * SZ_FEAT + SZ_AT + 2 * SZ_PB + SZ_AV) * sizeof(float);
  if (ws_size < need) return;  // insufficient scratch: fail visibly

  float* ws = (float*)d_ws;
  float* qb = ws;                 // also xo (in-place stage2 output)
  float* kb = qb + SZ_FEAT;       // also p-conv output
  float* vb = kb + SZ_FEAT;
  float* at = vb + SZ_FEAT;
  float* pb = at + SZ_AT;
  float* ab = pb + SZ_PB;
  float* av = ab + SZ_PB;

  const dim3 cgrid(NPIX / 64, CC / 64, BB);
  const dim3 ggrid(NGROUPS, BB);

  conv1x1_kernel<<<cgrid, 256, 0, stream>>>(x, q_w, qb);
  gn_kernel<<<ggrid, 256, 0, stream>>>(qb, q_gw, q_gb, qb);
  conv1x1_kernel<<<cgrid, 256, 0, stream>>>(x, k_w, kb);
  gn_kernel<<<ggrid, 256, 0, stream>>>(kb, k_gw, k_gb, kb);
  conv1x1_kernel<<<cgrid, 256, 0, stream>>>(x, v_w, vb);
  gn_kernel<<<ggrid, 256, 0, stream>>>(vb, v_gw, v_gb, vb);

  pool_kernel<<<BB * CC, 64, 0, stream>>>(qb, at);
  bias1_kernel<<<NHEADS * AG, 256, 0, stream>>>(an_b, ah_b, aw_b, pb);
  bias2_kernel<<<NHEADS * AG, 256, 0, stream>>>(na_b, ha_b, wa_b, ab);

  stage1_kernel<<<BB * NHEADS * AG, 256, 0, stream>>>(kb, vb, at, pb, av);
  stage2_kernel<<<dim3(13, NHEADS, BB), 256, 0, stream>>>(qb, at, av, ab, qb);
  dwconv_kernel<<<BB * CC, 256, 0, stream>>>(vb, dwc_w, dwc_b, qb);

  conv1x1_kernel<<<cgrid, 256, 0, stream>>>(qb, p_w, kb);
  gn_kernel<<<ggrid, 256, 0, stream>>>(kb, p_gw, p_gb, out);
}

// Round 4
// 2717.809 us; speedup vs baseline: 1.0605x; 1.0605x over previous
//
#include <hip/hip_runtime.h>
#include <hip/hip_bf16.h>
#include <math.h>

#define BB      32
#define CC      256
#define HDIM    56
#define NPIX    3136
#define NHEADS  8
#define HD      32
#define AG      49
#define NGROUPS 32
#define CPG     8
#define SCALE   0.17677669529663687f

// ---------------- conv1x1: Y[b][o][n] = sum_c W[o][c] * X[b][c][n] ----------
// per-batch GEMM M=256,K=256,N=3136; 64x64 tile, BK=16, 256 thr, 4x4/thread
__global__ __launch_bounds__(256) void conv1x1_kernel(
    const float* __restrict__ X, const float* __restrict__ W,
    float* __restrict__ Y) {
  __shared__ float Ws[16][64];
  __shared__ float Xs[16][64];
  const int n0 = blockIdx.x * 64;
  const int o0 = blockIdx.y * 64;
  const int b  = blockIdx.z;
  const float* Xb = X + (size_t)b * CC * NPIX;
  float* Yb = Y + (size_t)b * CC * NPIX;
  const int tid = threadIdx.x;
  const int tx = tid & 15, ty = tid >> 4;
  const int wo = tid >> 2, wk = (tid & 3) << 2;
  const int xk = tid >> 4, xn = (tid & 15) << 2;
  float acc[4][4] = {};
  for (int k0 = 0; k0 < CC; k0 += 16) {
    float4 wv = *(const float4*)&W[(size_t)(o0 + wo) * CC + k0 + wk];
    Ws[wk + 0][wo] = wv.x; Ws[wk + 1][wo] = wv.y;
    Ws[wk + 2][wo] = wv.z; Ws[wk + 3][wo] = wv.w;
    *(float4*)&Xs[xk][xn] =
        *(const float4*)&Xb[(size_t)(k0 + xk) * NPIX + n0 + xn];
    __syncthreads();
#pragma unroll
    for (int kk = 0; kk < 16; ++kk) {
      const float a0 = Ws[kk][ty * 4 + 0];
      const float a1 = Ws[kk][ty * 4 + 1];
      const float a2 = Ws[kk][ty * 4 + 2];
      const float a3 = Ws[kk][ty * 4 + 3];
      const float4 bv = *(const float4*)&Xs[kk][tx * 4];
      acc[0][0] += a0 * bv.x; acc[0][1] += a0 * bv.y;
      acc[0][2] += a0 * bv.z; acc[0][3] += a0 * bv.w;
      acc[1][0] += a1 * bv.x; acc[1][1] += a1 * bv.y;
      acc[1][2] += a1 * bv.z; acc[1][3] += a1 * bv.w;
      acc[2][0] += a2 * bv.x; acc[2][1] += a2 * bv.y;
      acc[2][2] += a2 * bv.z; acc[2][3] += a2 * bv.w;
      acc[3][0] += a3 * bv.x; acc[3][1] += a3 * bv.y;
      acc[3][2] += a3 * bv.z; acc[3][3] += a3 * bv.w;
    }
    __syncthreads();
  }
#pragma unroll
  for (int i = 0; i < 4; ++i) {
    float4 r = make_float4(acc[i][0], acc[i][1], acc[i][2], acc[i][3]);
    *(float4*)&Yb[(size_t)(o0 + ty * 4 + i) * NPIX + n0 + tx * 4] = r;
  }
}

// ---------------- GroupNorm (in-place capable): one block per (b, g) --------
__global__ __launch_bounds__(256) void gn_kernel(
    const float* __restrict__ in, const float* __restrict__ gw,
    const float* __restrict__ gb, float* __restrict__ out) {
  const int g = blockIdx.x, b = blockIdx.y;
  const float* p = in + ((size_t)b * CC + g * CPG) * NPIX;
  float* q = out + ((size_t)b * CC + g * CPG) * NPIX;
  const int tid = threadIdx.x;
  const int M4 = CPG * NPIX / 4;  // 6272 float4s
  const float4* p4 = (const float4*)p;
  float4* q4 = (float4*)q;
  float s = 0.f, ss = 0.f;
  for (int i = tid; i < M4; i += 256) {
    float4 v = p4[i];
    s += v.x + v.y + v.z + v.w;
    ss += v.x * v.x + v.y * v.y + v.z * v.z + v.w * v.w;
  }
#pragma unroll
  for (int off = 32; off > 0; off >>= 1) {
    s += __shfl_down(s, off);
    ss += __shfl_down(ss, off);
  }
  __shared__ float wsum[4], wsq[4], stat[2];
  const int wv = tid >> 6, ln = tid & 63;
  if (ln == 0) { wsum[wv] = s; wsq[wv] = ss; }
  __syncthreads();
  if (tid == 0) {
    float S = wsum[0] + wsum[1] + wsum[2] + wsum[3];
    float SS = wsq[0] + wsq[1] + wsq[2] + wsq[3];
    const float inv_m = 1.f / (CPG * NPIX);
    float mean = S * inv_m;
    float var = SS * inv_m - mean * mean;
    stat[0] = mean;
    stat[1] = rsqrtf(var + 1e-5f);
  }
  __syncthreads();
  const float mean = stat[0], inv = stat[1];
  for (int i = tid; i < M4; i += 256) {
    const int ch = g * CPG + i / (NPIX / 4);
    const float w = gw[ch] * inv, bia = gb[ch];
    float4 v = p4[i];
    v.x = (v.x - mean) * w + bia;
    v.y = (v.y - mean) * w + bia;
    v.z = (v.z - mean) * w + bia;
    v.w = (v.w - mean) * w + bia;
    q4[i] = v;
  }
}

// ---------------- agent-token pool: 8x8 avg -> (B,C,49) ---------------------
__global__ __launch_bounds__(64) void pool_kernel(const float* __restrict__ q,
                                                  float* __restrict__ at) {
  const int bc = blockIdx.x;
  const int a = threadIdx.x;
  if (a >= AG) return;
  const int py = a / 7, px = a % 7;
  const float* p = q + (size_t)bc * NPIX + (py * 8) * HDIM + px * 8;
  float s = 0.f;
#pragma unroll
  for (int y = 0; y < 8; ++y)
#pragma unroll
    for (int x = 0; x < 8; ++x) s += p[y * HDIM + x];
  at[(size_t)bc * AG + a] = s * (1.f / 64.f);
}

// ---------------- bias precompute -------------------------------------------
// bilinear 7->56 with half-pixel centers == clamped-coordinate bilinear
__device__ __forceinline__ float bilin7(const float* __restrict__ src, int y,
                                        int x) {
  float sy = fminf(fmaxf((y + 0.5f) * 0.125f - 0.5f, 0.f), 6.f);
  float sx = fminf(fmaxf((x + 0.5f) * 0.125f - 0.5f, 0.f), 6.f);
  int y0 = (int)sy, x0 = (int)sx;
  int y1 = min(y0 + 1, 6), x1 = min(x0 + 1, 6);
  float fy = sy - y0, fx = sx - x0;
  return (1.f - fy) * ((1.f - fx) * src[y0 * 7 + x0] + fx * src[y0 * 7 + x1]) +
         fy * ((1.f - fx) * src[y1 * 7 + x0] + fx * src[y1 * 7 + x1]);
}

// pbt[h][n][a] = resize(an_bias)[h,a,n] + ah[h,a,y] + aw[h,a,x]  (TRANSPOSED)
__global__ __launch_bounds__(256) void bias1_kernel(
    const float* __restrict__ an, const float* __restrict__ ah,
    const float* __restrict__ aw, float* __restrict__ pbt) {
  const int ha = blockIdx.x;  // h*AG + a
  const int h = ha / AG, a = ha % AG;
  const float* src = an + (size_t)ha * 49;
  const float* ahp = ah + (size_t)ha * HDIM;
  const float* awp = aw + (size_t)ha * HDIM;
  for (int n = threadIdx.x; n < NPIX; n += 256) {
    const int y = n / HDIM, x = n % HDIM;
    pbt[((size_t)h * NPIX + n) * AG + a] = bilin7(src, y, x) + ahp[y] + awp[x];
  }
}

// ab[h][n][a] = resize(na_bias)[h,a,n] + ha[h,y,a] + wa[h,x,a]
__global__ __launch_bounds__(256) void bias2_kernel(
    const float* __restrict__ na, const float* __restrict__ hab,
    const float* __restrict__ wab, float* __restrict__ ab) {
  const int ha = blockIdx.x;  // h*AG + a
  const int h = ha / AG, a = ha % AG;
  const float* src = na + (size_t)ha * 49;
  for (int n = threadIdx.x; n < NPIX; n += 256) {
    const int y = n / HDIM, x = n % HDIM;
    ab[((size_t)h * NPIX + n) * AG + a] =
        bilin7(src, y, x) + hab[((size_t)h * HDIM + y) * AG + a] +
        wab[((size_t)h * HDIM + x) * AG + a];
  }
}

// ---------------- stage 1 v2: one block per (b,h); lane = agent -------------
// 512 thr = 8 waves; wave w owns n-chunks {w, w+8, ...} of 4 pixels each.
// Online softmax per lane; per-wave partial states combined in LDS.
// K/V reads are wave-broadcast float4 (same addr all lanes -> 1 request).
__global__ __launch_bounds__(512) void stage1_kernel(
    const float* __restrict__ K, const float* __restrict__ V,
    const float* __restrict__ at, const float* __restrict__ pbt,
    float* __restrict__ av) {
  const int b = blockIdx.x >> 3, h = blockIdx.x & 7;
  const int tid = threadIdx.x;
  const int w = tid >> 6;        // wave 0..7
  const int a = tid & 63;        // lane = agent (49 active)
  const int ar = a < AG ? a : AG - 1;

  const float* Kb = K + ((size_t)b * CC + h * HD) * NPIX;
  const float* Vb = V + ((size_t)b * CC + h * HD) * NPIX;
  const float* pbh = pbt + (size_t)h * NPIX * AG;

  float at_r[HD];
#pragma unroll
  for (int d = 0; d < HD; ++d)
    at_r[d] = at[((size_t)b * CC + h * HD + d) * AG + ar] * SCALE;

  float m = -1e30f, l = 0.f;
  float acc[HD];
#pragma unroll
  for (int d = 0; d < HD; ++d) acc[d] = 0.f;

  for (int c = w; c < NPIX / 4; c += 8) {
    const int n0 = c * 4;
    float4 s4;
    s4.x = pbh[(size_t)(n0 + 0) * AG + ar];
    s4.y = pbh[(size_t)(n0 + 1) * AG + ar];
    s4.z = pbh[(size_t)(n0 + 2) * AG + ar];
    s4.w = pbh[(size_t)(n0 + 3) * AG + ar];
#pragma unroll
    for (int d = 0; d < HD; ++d) {
      const float4 kv = *(const float4*)&Kb[(size_t)d * NPIX + n0];
      const float av_ = at_r[d];
      s4.x += av_ * kv.x; s4.y += av_ * kv.y;
      s4.z += av_ * kv.z; s4.w += av_ * kv.w;
    }
    const float smax = fmaxf(fmaxf(s4.x, s4.y), fmaxf(s4.z, s4.w));
    if (smax > m) {
      const float corr = __expf(m - smax);
      m = smax;
      l *= corr;
#pragma unroll
      for (int d = 0; d < HD; ++d) acc[d] *= corr;
    }
    const float e0 = __expf(s4.x - m), e1 = __expf(s4.y - m);
    const float e2 = __expf(s4.z - m), e3 = __expf(s4.w - m);
    l += (e0 + e1) + (e2 + e3);
#pragma unroll
    for (int d = 0; d < HD; ++d) {
      const float4 vv = *(const float4*)&Vb[(size_t)d * NPIX + n0];
      acc[d] += e0 * vv.x + e1 * vv.y + e2 * vv.z + e3 * vv.w;
    }
  }

  // ---- combine 8 per-wave partial states --------------------------------
  __shared__ float m_s[8][64];
  __shared__ float l_s[8][64];
  __shared__ float acc_s[8][AG][HD + 1];
  __shared__ float M_s[AG], inv_s[AG], wgt_s[8][AG];
  m_s[w][a] = (a < AG) ? m : -1e30f;
  l_s[w][a] = (a < AG) ? l : 0.f;
  if (a < AG) {
#pragma unroll
    for (int d = 0; d < HD; ++d) acc_s[w][a][d] = acc[d];
  }
  __syncthreads();
  if (tid < AG) {
    float M = m_s[0][tid];
#pragma unroll
    for (int i = 1; i < 8; ++i) M = fmaxf(M, m_s[i][tid]);
    float L = 0.f;
#pragma unroll
    for (int i = 0; i < 8; ++i) {
      const float wg = __expf(m_s[i][tid] - M);
      wgt_s[i][tid] = wg;
      L += l_s[i][tid] * wg;
    }
    M_s[tid] = M;
    inv_s[tid] = 1.f / L;
  }
  __syncthreads();
  for (int i = tid; i < AG * HD; i += 512) {
    const int aa = i >> 5, d = i & 31;
    float s = 0.f;
#pragma unroll
    for (int ww = 0; ww < 8; ++ww) s += acc_s[ww][aa][d] * wgt_s[ww][aa];
    av[(((size_t)b * NHEADS + h) * AG + aa) * HD + d] = s * inv_s[aa];
  }
}

// ---------------- stage 2: queries attend to agents; writes xo in place -----
// grid (13, HEADS, B), 256 thr; thread = one pixel n
__global__ __launch_bounds__(256) void stage2_kernel(
    const float* __restrict__ Q, const float* __restrict__ at,
    const float* __restrict__ av, const float* __restrict__ ab,
    float* __restrict__ XO) {
  const int tid = threadIdx.x;
  const int n = blockIdx.x * 256 + tid;
  const int h = blockIdx.y, b = blockIdx.z;
  __shared__ float at_s[AG][HD];
  __shared__ float av_s[AG][HD];
  for (int i = tid; i < AG * HD; i += 256) {
    const int a = i / HD, d = i % HD;
    at_s[a][d] = at[((size_t)b * CC + h * HD + d) * AG + a];
    av_s[a][d] = av[(((size_t)b * NHEADS + h) * AG + a) * HD + d];
  }
  __syncthreads();
  if (n >= NPIX) return;
  const float* Qb = Q + ((size_t)b * CC + h * HD) * NPIX;
  float* Ob = XO + ((size_t)b * CC + h * HD) * NPIX;
  float qv[HD];
#pragma unroll
  for (int d = 0; d < HD; ++d) qv[d] = Qb[(size_t)d * NPIX + n] * SCALE;
  const float* abp = ab + ((size_t)h * NPIX + n) * AG;
  // pass 1: max
  float m = -1e30f;
  for (int a = 0; a < AG; ++a) {
    float s = abp[a];
#pragma unroll
    for (int d = 0; d < HD; ++d) s += qv[d] * at_s[a][d];
    m = fmaxf(m, s);
  }
  // pass 2: exp-sum + PV accumulate
  float sum = 0.f;
  float o[HD];
#pragma unroll
  for (int d = 0; d < HD; ++d) o[d] = 0.f;
  for (int a = 0; a < AG; ++a) {
    float s = abp[a];
#pragma unroll
    for (int d = 0; d < HD; ++d) s += qv[d] * at_s[a][d];
    const float e = __expf(s - m);
    sum += e;
#pragma unroll
    for (int d = 0; d < HD; ++d) o[d] += e * av_s[a][d];
  }
  const float inv = 1.f / sum;
#pragma unroll
  for (int d = 0; d < HD; ++d) Ob[(size_t)d * NPIX + n] = o[d] * inv;
}

// ---------------- depthwise 3x3 conv on v, accumulate into XO ---------------
__global__ __launch_bounds__(256) void dwconv_kernel(
    const float* __restrict__ V, const float* __restrict__ w,
    const float* __restrict__ bias, float* __restrict__ XO) {
  const int bc = blockIdx.x;
  const int c = bc % CC;
  const float* src = V + (size_t)bc * NPIX;
  float* dst = XO + (size_t)bc * NPIX;
  float k[9];
#pragma unroll
  for (int i = 0; i < 9; ++i) k[i] = w[c * 9 + i];
  const float bb = bias[c];
  for (int n = threadIdx.x; n < NPIX; n += 256) {
    const int y = n / HDIM, x = n % HDIM;
    float s = bb;
#pragma unroll
    for (int ky = 0; ky < 3; ++ky) {
      const int yy = y + ky - 1;
      if (yy < 0 || yy >= HDIM) continue;
#pragma unroll
      for (int kx = 0; kx < 3; ++kx) {
        const int xx = x + kx - 1;
        if (xx < 0 || xx >= HDIM) continue;
        s += src[yy * HDIM + xx] * k[ky * 3 + kx];
      }
    }
    dst[n] += s;
  }
}

// ---------------- host launch ------------------------------------------------
extern "C" void kernel_launch(void* const* d_in, const int* in_sizes, int n_in,
                              void* d_out, int out_size, void* d_ws,
                              size_t ws_size, hipStream_t stream) {
  const float* x     = (const float*)d_in[0];
  const float* q_w   = (const float*)d_in[1];
  const float* q_gw  = (const float*)d_in[2];
  const float* q_gb  = (const float*)d_in[3];
  const float* k_w   = (const float*)d_in[4];
  const float* k_gw  = (const float*)d_in[5];
  const float* k_gb  = (const float*)d_in[6];
  const float* v_w   = (const float*)d_in[7];
  const float* v_gw  = (const float*)d_in[8];
  const float* v_gb  = (const float*)d_in[9];
  const float* p_w   = (const float*)d_in[10];
  const float* p_gw  = (const float*)d_in[11];
  const float* p_gb  = (const float*)d_in[12];
  const float* dwc_w = (const float*)d_in[13];
  const float* dwc_b = (const float*)d_in[14];
  const float* an_b  = (const float*)d_in[15];
  const float* na_b  = (const float*)d_in[16];
  const float* ah_b  = (const float*)d_in[17];
  const float* aw_b  = (const float*)d_in[18];
  const float* ha_b  = (const float*)d_in[19];
  const float* wa_b  = (const float*)d_in[20];
  float* out = (float*)d_out;

  const size_t SZ_FEAT = (size_t)BB * CC * NPIX;       // 25,690,112 floats
  const size_t SZ_AT   = (size_t)BB * CC * AG;         // 401,408
  const size_t SZ_PB   = (size_t)NHEADS * AG * NPIX;   // 1,229,312
  const size_t SZ_AV   = (size_t)BB * NHEADS * AG * HD;
  const size_t need = (3 * SZ_FEAT + SZ_AT + 2 * SZ_PB + SZ_AV) * sizeof(float);
  if (ws_size < need) return;  // insufficient scratch: fail visibly

  float* ws = (float*)d_ws;
  float* qb = ws;                 // also xo (in-place stage2 output)
  float* kb = qb + SZ_FEAT;       // also p-conv output
  float* vb = kb + SZ_FEAT;
  float* at = vb + SZ_FEAT;
  float* pbt = at + SZ_AT;        // stage-1 bias, [h][n][a] transposed
  float* ab = pbt + SZ_PB;
  float* av = ab + SZ_PB;

  const dim3 cgrid(NPIX / 64, CC / 64, BB);
  const dim3 ggrid(NGROUPS, BB);

  conv1x1_kernel<<<cgrid, 256, 0, stream>>>(x, q_w, qb);
  gn_kernel<<<ggrid, 256, 0, stream>>>(qb, q_gw, q_gb, qb);
  conv1x1_kernel<<<cgrid, 256, 0, stream>>>(x, k_w, kb);
  gn_kernel<<<ggrid, 256, 0, stream>>>(kb, k_gw, k_gb, kb);
  conv1x1_kernel<<<cgrid, 256, 0, stream>>>(x, v_w, vb);
  gn_kernel<<<ggrid, 256, 0, stream>>>(vb, v_gw, v_gb, vb);

  pool_kernel<<<BB * CC, 64, 0, stream>>>(qb, at);
  bias1_kernel<<<NHEADS * AG, 256, 0, stream>>>(an_b, ah_b, aw_b, pbt);
  bias2_kernel<<<NHEADS * AG, 256, 0, stream>>>(na_b, ha_b, wa_b, ab);

  stage1_kernel<<<BB * NHEADS, 512, 0, stream>>>(kb, vb, at, pbt, av);
  stage2_kernel<<<dim3(13, NHEADS, BB), 256, 0, stream>>>(qb, at, av, ab, qb);
  dwconv_kernel<<<BB * CC, 256, 0, stream>>>(vb, dwc_w, dwc_b, qb);

  conv1x1_kernel<<<cgrid, 256, 0, stream>>>(qb, p_w, kb);
  gn_kernel<<<ggrid, 256, 0, stream>>>(kb, p_gw, p_gb, out);
}